// Round 4
// baseline (2147.228 us; speedup 1.0000x reference)
//
#include <hip/hip_runtime.h>
#include <math.h>

typedef unsigned long long u64;
typedef unsigned int u32;

// Problem constants
#define L 512
#define E 300
#define H 512          // per-direction hidden
#define G4H 2048       // 4*H
#define NTAGS 20
#define START_TAG 18
#define STOP_TAG 19

#define TR 8           // t-rows per k1 block

// Workspace layout (bytes)
#define OFF_XW    0u          // f32 [2][512][2048] (permuted cols) = 8388608
#define OFF_HIST  8388608u    // f32 [2][512][512]  = 2097152
#define OFF_HBUF  10485760u   // u64 [2][2][512]    = 16384
#define OFF_FEATS 10502144u   // f32 [512][20]      = 40960

// ---------------------------------------------------------------------------
// K1: xw[dir][t][pos(n)] = embed[sent[t]] . wih[n] + bih[n]+bhh[n]   (f32)
// Column permutation pos(n) groups the 8 gate-rows each k2 wave consumes into
// one contiguous 32B chunk: u=n&511, gate=n>>9, pos=(u>>1)*8+gate*2+(u&1).
__global__ void k1_xw(const int* __restrict__ sentence,
                      const float* __restrict__ embed,
                      const float* __restrict__ wih_f, const float* __restrict__ wih_b,
                      const float* __restrict__ bih_f, const float* __restrict__ bhh_f,
                      const float* __restrict__ bih_b, const float* __restrict__ bhh_b,
                      float* __restrict__ xw) {
    __shared__ float xs[TR][304];
    int tid = threadIdx.x;
    int n   = blockIdx.x * 256 + tid;
    int t0  = blockIdx.y * TR;
    int dir = blockIdx.z;
    const float* wih = dir ? wih_b : wih_f;
    const float* bih = dir ? bih_b : bih_f;
    const float* bhh = dir ? bhh_b : bhh_f;

    for (int r = 0; r < TR; ++r)
        for (int k = tid; k < E; k += 256)
            xs[r][k] = embed[(size_t)sentence[t0 + r] * E + k];
    __syncthreads();

    const float* wrow = wih + (size_t)n * E;
    float acc[TR];
#pragma unroll
    for (int r = 0; r < TR; ++r) acc[r] = 0.f;

    for (int kk = 0; kk < E / 4; ++kk) {
        float4 wv = ((const float4*)wrow)[kk];
#pragma unroll
        for (int r = 0; r < TR; ++r) {
            float4 xv = *(const float4*)(&xs[r][kk * 4]);
            acc[r] = fmaf(wv.x, xv.x, fmaf(wv.y, xv.y,
                     fmaf(wv.z, xv.z, fmaf(wv.w, xv.w, acc[r]))));
        }
    }
    float b = bih[n] + bhh[n];
    int u = n & (H - 1), gate = n >> 9;
    int pos = (u >> 1) * 8 + gate * 2 + (u & 1);
#pragma unroll
    for (int r = 0; r < TR; ++r)
        xw[((size_t)(dir * L) + (t0 + r)) * G4H + pos] = acc[r] + b;
}

// ---------------------------------------------------------------------------
// K2: bidirectional LSTM recurrence. One wave per block, 256 blocks (1/CU).
// Wave g2 owns hidden units {2*g2, 2*g2+1} of BOTH directions (8 gate rows x
// full K each, 128 weight VGPRs). Lane l: row j=l&7, k-slice q=l>>3.
// h exchange: tagged u64 slots, relaxed agent atomics (no cache maintenance);
// slot index for unit u: ((u&7)>>1)*128 + (u>>3)*2 + (u&1)  ->  consumer lane
// l reads slots for units 8l..8l+8 with 4 coalesced index groups.
// Both directions' polls issue together: one fabric RT covers both.
__global__ __launch_bounds__(64) void k2_lstm(
    const float* __restrict__ whh_f, const float* __restrict__ whh_b,
    const float* __restrict__ h0, const float* __restrict__ c0,
    const float* __restrict__ xw, float* __restrict__ hist,
    u64* __restrict__ hbuf) {
    const int g2 = blockIdx.x;          // 0..255
    const int l  = threadIdx.x;         // 0..63
    const int j  = l & 7;               // local gate row
    const int q  = l >> 3;              // k-slice
    const int u0 = g2 * 2;
    const int row = (j >> 1) * H + u0 + (j & 1);

    // weights -> VGPRs (one-time)
    float w0[64], w1[64];
    {
        const float* p0 = whh_f + (size_t)row * H + q * 64;
        const float* p1 = whh_b + (size_t)row * H + q * 64;
#pragma unroll
        for (int i = 0; i < 64; i += 4) {
            float4 a = *(const float4*)(p0 + i);
            w0[i] = a.x; w0[i+1] = a.y; w0[i+2] = a.z; w0[i+3] = a.w;
            float4 b = *(const float4*)(p1 + i);
            w1[i] = b.x; w1[i+1] = b.y; w1[i+2] = b.z; w1[i+3] = b.w;
        }
    }

    // wave-private LDS staging; row stride 68 floats -> slice q hits banks
    // 4q..4q+3 (conflict-free across the 8 slice-groups)
    __shared__ float hstage[2][8 * 68];

    // c state: lanes 0,1 = dir0 units; lanes 8,9 = dir1 units
    float c = 0.f;
    if (l < 2)                 c = c0[u0 + l];
    else if (l >= 8 && l < 10) c = c0[H + u0 + (l - 8)];

    u64* hb0 = hbuf;            // [parity][512]
    u64* hb1 = hbuf + 1024;
    const int cons_base = l * 2;              // consumer slot base for this lane
    const int prod_idx  = (g2 & 3) * 128 + (g2 >> 2) * 2;   // producer slots

    for (int s = 1; s <= L; ++s) {
        const int t0 = s - 1, t1 = L - s;

        // xw prefetch (lanes 0..15): dir = l>>3, row j = l&7
        float xwv = 0.f;
        if (l < 16) {
            int d = l >> 3;
            xwv = xw[((size_t)(d * L + (d ? t1 : t0))) * G4H + g2 * 8 + (l & 7)];
        }

        // ---- acquire h_{s-1} for both dirs ----
        float p0[8], p1[8];
        if (s == 1) {
            const float4* A = (const float4*)h0;
            float4 a0 = A[2 * l], a1 = A[2 * l + 1];
            p0[0]=a0.x; p0[1]=a0.y; p0[2]=a0.z; p0[3]=a0.w;
            p0[4]=a1.x; p0[5]=a1.y; p0[6]=a1.z; p0[7]=a1.w;
            const float4* B = (const float4*)(h0 + H);
            float4 b0 = B[2 * l], b1 = B[2 * l + 1];
            p1[0]=b0.x; p1[1]=b0.y; p1[2]=b0.z; p1[3]=b0.w;
            p1[4]=b1.x; p1[5]=b1.y; p1[6]=b1.z; p1[7]=b1.w;
        } else {
            const u32 tag = (u32)(s - 1);
            u64* b0 = hb0 + ((s - 1) & 1) * 512;
            u64* b1 = hb1 + ((s - 1) & 1) * 512;
            u64 v0[8], v1[8];
#pragma unroll
            for (int r = 0; r < 8; ++r)
                v0[r] = __hip_atomic_load(b0 + (r >> 1) * 128 + cons_base + (r & 1),
                                          __ATOMIC_RELAXED, __HIP_MEMORY_SCOPE_AGENT);
#pragma unroll
            for (int r = 0; r < 8; ++r)
                v1[r] = __hip_atomic_load(b1 + (r >> 1) * 128 + cons_base + (r & 1),
                                          __ATOMIC_RELAXED, __HIP_MEMORY_SCOPE_AGENT);
            for (;;) {
                bool ok = true;
#pragma unroll
                for (int r = 0; r < 8; ++r) ok &= ((u32)(v0[r] >> 32) == tag);
                if (__all(ok)) break;
                __builtin_amdgcn_s_sleep(1);
#pragma unroll
                for (int r = 0; r < 8; ++r)
                    v0[r] = __hip_atomic_load(b0 + (r >> 1) * 128 + cons_base + (r & 1),
                                              __ATOMIC_RELAXED, __HIP_MEMORY_SCOPE_AGENT);
            }
            for (;;) {
                bool ok = true;
#pragma unroll
                for (int r = 0; r < 8; ++r) ok &= ((u32)(v1[r] >> 32) == tag);
                if (__all(ok)) break;
                __builtin_amdgcn_s_sleep(1);
#pragma unroll
                for (int r = 0; r < 8; ++r)
                    v1[r] = __hip_atomic_load(b1 + (r >> 1) * 128 + cons_base + (r & 1),
                                              __ATOMIC_RELAXED, __HIP_MEMORY_SCOPE_AGENT);
            }
#pragma unroll
            for (int r = 0; r < 8; ++r) p0[r] = __uint_as_float((u32)v0[r]);
#pragma unroll
            for (int r = 0; r < 8; ++r) p1[r] = __uint_as_float((u32)v1[r]);
        }

        // stage to LDS (wave-private: no barrier, lgkmcnt only)
        {
            int wbase = q * 68 + 8 * j;   // units 8l..8l+8 live in slice q=l>>3
            *(__shared__ float4*)&hstage[0][wbase]     = make_float4(p0[0], p0[1], p0[2], p0[3]);
            *(__shared__ float4*)&hstage[0][wbase + 4] = make_float4(p0[4], p0[5], p0[6], p0[7]);
            *(__shared__ float4*)&hstage[1][wbase]     = make_float4(p1[0], p1[1], p1[2], p1[3]);
            *(__shared__ float4*)&hstage[1][wbase + 4] = make_float4(p1[4], p1[5], p1[6], p1[7]);
        }

        // dot: row j, slice q, both dirs interleaved (LDS pipe || VALU)
        float acc0 = 0.f, acc1 = 0.f;
#pragma unroll
        for (int i = 0; i < 64; i += 4) {
            float4 h4 = *(__shared__ float4*)&hstage[0][q * 68 + i];
            acc0 = fmaf(w0[i], h4.x, fmaf(w0[i+1], h4.y,
                   fmaf(w0[i+2], h4.z, fmaf(w0[i+3], h4.w, acc0))));
            float4 g4 = *(__shared__ float4*)&hstage[1][q * 68 + i];
            acc1 = fmaf(w1[i], g4.x, fmaf(w1[i+1], g4.y,
                   fmaf(w1[i+2], g4.z, fmaf(w1[i+3], g4.w, acc1))));
        }
        // reduce over k-slices (butterfly over lanes stride 8,16,32)
        acc0 += __shfl_xor(acc0, 8);  acc0 += __shfl_xor(acc0, 16); acc0 += __shfl_xor(acc0, 32);
        acc1 += __shfl_xor(acc1, 8);  acc1 += __shfl_xor(acc1, 16); acc1 += __shfl_xor(acc1, 32);

        // gates on lanes 0..15 (0..7 dir0, 8..15 dir1); every lane has its row's sum
        float pre  = ((l < 8) ? acc0 : acc1) + xwv;
        int   gate = (l & 7) >> 1;
        float a2 = (gate == 2) ? 2.f * pre : pre;     // tanh = 2*sig(2x)-1
        float sg = 1.f / (1.f + __expf(-a2));
        float vg = (gate == 2) ? (2.f * sg - 1.f) : sg;

        // unit update on lanes 0,1 (dir0) and 8,9 (dir1)
        float gi = __shfl(vg, (l & 8) + 0 + (l & 1));
        float gf = __shfl(vg, (l & 8) + 2 + (l & 1));
        float gg = __shfl(vg, (l & 8) + 4 + (l & 1));
        float go = __shfl(vg, (l & 8) + 6 + (l & 1));
        float hval = 0.f;
        bool upd = (l < 2) || (l >= 8 && l < 10);
        if (upd) {
            c = gf * c + gi * gg;
            float th = 2.f / (1.f + __expf(-2.f * c)) - 1.f;
            hval = go * th;
        }
        // tagged publish first (critical path), hist after
        float hnb = __shfl(hval, (l + 1) & 63);
        if (l == 0 || l == 8) {
            u64* bb = (l ? hb1 : hb0) + (s & 1) * 512 + prod_idx;
            u64 e0 = ((u64)(u32)s << 32) | (u64)(u32)__float_as_uint(hval);
            u64 e1 = ((u64)(u32)s << 32) | (u64)(u32)__float_as_uint(hnb);
            __hip_atomic_store(bb,     e0, __ATOMIC_RELAXED, __HIP_MEMORY_SCOPE_AGENT);
            __hip_atomic_store(bb + 1, e1, __ATOMIC_RELAXED, __HIP_MEMORY_SCOPE_AGENT);
        }
        if (upd) {
            int d = l >> 3;
            hist[((size_t)(d * L + (d ? t1 : t0))) * H + u0 + (l & 1)] = hval;
        }
    }
}

// ---------------------------------------------------------------------------
// K3: feats[t][tag] = b_out[tag] + concat(hf,hb)[t] . w_out[tag]   (f32)
__global__ void k3_feats(const float* __restrict__ hist,
                         const float* __restrict__ wout,
                         const float* __restrict__ bout,
                         float* __restrict__ feats) {
    int t = blockIdx.x;
    int tid = threadIdx.x;
    int tag = tid >> 4;       // [0,20)
    int part = tid & 15;
    const float* h0p = hist + (size_t)t * H;
    const float* h1p = hist + (size_t)L * H + (size_t)t * H;
    int j0 = part * 64;
    float acc = 0.f;
    for (int jj = 0; jj < 64; jj += 4) {
        int j = j0 + jj;
        float4 w4 = *(const float4*)(wout + (size_t)tag * (2 * H) + j);
        float4 h4 = (j < H) ? *(const float4*)(h0p + j)
                            : *(const float4*)(h1p + (j - H));
        acc = fmaf(w4.x, h4.x, fmaf(w4.y, h4.y,
              fmaf(w4.z, h4.z, fmaf(w4.w, h4.w, acc))));
    }
    acc += __shfl_xor(acc, 8, 16);
    acc += __shfl_xor(acc, 4, 16);
    acc += __shfl_xor(acc, 2, 16);
    acc += __shfl_xor(acc, 1, 16);
    if (part == 0) feats[(size_t)t * NTAGS + tag] = acc + bout[tag];
}

// ---------------------------------------------------------------------------
// K4: Viterbi + backtrack, one wave. Batched shfls + index-carrying tree-max
// (exact first-max semantics: replace only on (v>) or (v== && idx<)).
__global__ void k4_viterbi(const float* __restrict__ feats,
                           const float* __restrict__ trans,
                           int* __restrict__ out) {
    __shared__ unsigned char bp[L * NTAGS];
    int lane = threadIdx.x;           // 64 threads
    bool act = lane < NTAGS;

    float trl[NTAGS];
#pragma unroll
    for (int p = 0; p < NTAGS; ++p)
        trl[p] = act ? trans[lane * NTAGS + p] : -1.0e30f;

    float fv = (lane == START_TAG) ? 0.f : -10000.f;
    float nf = act ? feats[lane] : 0.f;

    for (int t = 0; t < L; ++t) {
        float f = nf;
        if (act && t + 1 < L) nf = feats[(size_t)(t + 1) * NTAGS + lane];
        float tv[NTAGS];
        int   ti[NTAGS];
#pragma unroll
        for (int p = 0; p < NTAGS; ++p) {
            tv[p] = __shfl(fv, p) + trl[p];   // independent shfls, batch-issued
            ti[p] = p;
        }
        // first-max tree: 20 -> 16 -> 8 -> 4 -> 2 -> 1
#pragma unroll
        for (int p = 0; p < 4; ++p) {
            bool take = (tv[p + 16] > tv[p]) ||
                        (tv[p + 16] == tv[p] && ti[p + 16] < ti[p]);
            if (take) { tv[p] = tv[p + 16]; ti[p] = ti[p + 16]; }
        }
#pragma unroll
        for (int w = 8; w >= 1; w >>= 1)
#pragma unroll
            for (int p = 0; p < 16; ++p) if (p < w) {
                bool take = (tv[p + w] > tv[p]) ||
                            (tv[p + w] == tv[p] && ti[p + w] < ti[p]);
                if (take) { tv[p] = tv[p + w]; ti[p] = ti[p + w]; }
            }
        fv = tv[0] + f;
        if (act) bp[t * NTAGS + lane] = (unsigned char)ti[0];
    }

    // terminal argmax across lanes (keeps lower lane on ties)
    float ts = act ? fv + trans[STOP_TAG * NTAGS + lane] : -1.0e30f;
    int bi = lane;
#pragma unroll
    for (int off = 32; off; off >>= 1) {
        float ov = __shfl_down(ts, off);
        int   oi = __shfl_down(bi, off);
        if (ov > ts) { ts = ov; bi = oi; }
    }
    if (lane == 0) {
        int tag = bi;
        out[L - 1] = tag;
        for (int t = L - 1; t >= 1; --t) {
            tag = bp[t * NTAGS + tag];
            out[t - 1] = tag;
        }
    }
}

// ---------------------------------------------------------------------------
extern "C" void kernel_launch(void* const* d_in, const int* in_sizes, int n_in,
                              void* d_out, int out_size, void* d_ws, size_t ws_size,
                              hipStream_t stream) {
    const int*   sentence = (const int*)d_in[0];
    const float* embed    = (const float*)d_in[1];
    const float* wih_f    = (const float*)d_in[2];
    const float* whh_f    = (const float*)d_in[3];
    const float* bih_f    = (const float*)d_in[4];
    const float* bhh_f    = (const float*)d_in[5];
    const float* wih_b    = (const float*)d_in[6];
    const float* whh_b    = (const float*)d_in[7];
    const float* bih_b    = (const float*)d_in[8];
    const float* bhh_b    = (const float*)d_in[9];
    const float* h0       = (const float*)d_in[10];
    const float* c0       = (const float*)d_in[11];
    const float* wout     = (const float*)d_in[12];
    const float* bout     = (const float*)d_in[13];
    const float* trans    = (const float*)d_in[14];
    int* out = (int*)d_out;

    char* ws = (char*)d_ws;
    float* xw    = (float*)(ws + OFF_XW);
    float* hist  = (float*)(ws + OFF_HIST);
    float* feats = (float*)(ws + OFF_FEATS);
    u64*   hbuf  = (u64*)(ws + OFF_HBUF);

    k1_xw<<<dim3(8, 64, 2), 256, 0, stream>>>(sentence, embed, wih_f, wih_b,
                                              bih_f, bhh_f, bih_b, bhh_b, xw);
    // Plain (non-cooperative) launch: 256 blocks x 64 threads <= 256 CUs,
    // co-resident by capacity; tests the cooperative-launch-overhead theory.
    k2_lstm<<<256, 64, 0, stream>>>(whh_f, whh_b, h0, c0, xw, hist, hbuf);
    k3_feats<<<L, 320, 0, stream>>>(hist, wout, bout, feats);
    k4_viterbi<<<1, 64, 0, stream>>>(feats, trans, out);
}

// Round 5
// 1705.116 us; speedup vs baseline: 1.2593x; 1.2593x over previous
//
#include <hip/hip_runtime.h>
#include <math.h>

typedef unsigned long long u64;
typedef unsigned int u32;

// Problem constants
#define L 512
#define E 300
#define H 512          // per-direction hidden
#define G4H 2048       // 4*H
#define NTAGS 20
#define START_TAG 18
#define STOP_TAG 19

#define KC 100         // k1 K-chunk (300 = 3*100)

// Workspace layout (bytes)
#define OFF_XW    0u          // f32 [2][512][2048] (permuted cols) = 8388608
#define OFF_HIST  8388608u    // f32 [2][512][512]  = 2097152
#define OFF_HBUF  10485760u   // u64 [2][2][512]    = 16384
#define OFF_FEATS 10502144u   // f32 [512][20]      = 40960

// ---------------------------------------------------------------------------
// K1: tiled GEMM  xw[dir][t][pos(n)] = embed[sent[t]] . wih[n] + bias(n).
// 64n x 64t tile per block, 4x4 microtile, K chunks of 100 staged in LDS
// [k][n] / [k][t] (transposed at stage time -> conflict-free compute reads,
// coalesced global reads along K). Wih read 8x total (~39 MB), coalesced.
// Column permutation pos(n) groups each k2 wave's 8 gate-rows contiguously:
// u=n&511, g=n>>9 -> pos = (u>>4)*64 + ((u&15)>>1)*8 + g*2 + (u&1).
__global__ __launch_bounds__(256) void k1_xw(
    const int* __restrict__ sentence, const float* __restrict__ embed,
    const float* __restrict__ wih_f, const float* __restrict__ wih_b,
    const float* __restrict__ bih_f, const float* __restrict__ bhh_f,
    const float* __restrict__ bih_b, const float* __restrict__ bhh_b,
    float* __restrict__ xw) {
    __shared__ float wST[KC][68];   // [k][n], n-tile 64 (+4 pad)
    __shared__ float xST[KC][68];   // [k][t], t-tile 64 (+4 pad)
    __shared__ int   sT[64];

    const int tid = threadIdx.x;
    const int tx = tid & 15;        // t micro index
    const int ty = tid >> 4;        // n micro index
    const int n_base = blockIdx.x * 64;
    const int t_base = blockIdx.y * 64;
    const int dir = blockIdx.z;
    const float* wih = dir ? wih_b : wih_f;
    const float* bih = dir ? bih_b : bih_f;
    const float* bhh = dir ? bhh_b : bhh_f;

    if (tid < 64) sT[tid] = sentence[t_base + tid];
    __syncthreads();

    float acc[4][4];
#pragma unroll
    for (int i = 0; i < 4; ++i)
#pragma unroll
        for (int j = 0; j < 4; ++j) acc[i][j] = 0.f;

    for (int kc = 0; kc < E; kc += KC) {
        // stage W chunk: 64 rows x 100 cols, coalesced along col
#pragma unroll
        for (int i = 0; i < 25; ++i) {
            int idx = i * 256 + tid;          // < 6400
            int row = idx / KC, col = idx % KC;
            wST[col][row] = wih[(size_t)(n_base + row) * E + kc + col];
        }
        // stage x chunk: 64 t x 100 cols (embedding gather, coalesced per row)
#pragma unroll
        for (int i = 0; i < 25; ++i) {
            int idx = i * 256 + tid;
            int trow = idx / KC, col = idx % KC;
            xST[col][trow] = embed[(size_t)sT[trow] * E + kc + col];
        }
        __syncthreads();

#pragma unroll 4
        for (int k = 0; k < KC; ++k) {
            float4 wv4 = *(const float4*)&wST[k][ty * 4];
            float4 xv4 = *(const float4*)&xST[k][tx * 4];
            float wv[4] = {wv4.x, wv4.y, wv4.z, wv4.w};
            float xv[4] = {xv4.x, xv4.y, xv4.z, xv4.w};
#pragma unroll
            for (int i = 0; i < 4; ++i)
#pragma unroll
                for (int j = 0; j < 4; ++j)
                    acc[i][j] = fmaf(wv[i], xv[j], acc[i][j]);
        }
        __syncthreads();
    }

#pragma unroll
    for (int i = 0; i < 4; ++i) {
        int n = n_base + ty * 4 + i;
        float b = bih[n] + bhh[n];
        int u = n & (H - 1), g = n >> 9;
        int pos = (u >> 4) * 64 + ((u & 15) >> 1) * 8 + g * 2 + (u & 1);
#pragma unroll
        for (int j = 0; j < 4; ++j) {
            int t = t_base + tx * 4 + j;
            xw[((size_t)(dir * L) + t) * G4H + pos] = acc[i][j] + b;
        }
    }
}

// ---------------------------------------------------------------------------
// K2: bidirectional LSTM recurrence. 64 WGs x 512 threads (r3 topology).
// WG (dir,wg) owns units wg*16..+16. Wave wv owns units {wg*16+2wv, +1}:
// lane l -> gate row j=l&7 (gate g=j>>1, unit parity p=j&1), k-slice q=l>>3.
// Exchange: tagged u64 slots, relaxed agent atomics, parity double-buffer;
// each thread polls exactly ONE slot (unit tid). Per-step: one barrier,
// wave-autonomous gates+publish (no wave0 funnel).
__global__ __launch_bounds__(512) void k2_lstm(
    const float* __restrict__ whh_f, const float* __restrict__ whh_b,
    const float* __restrict__ h0, const float* __restrict__ c0,
    const float* __restrict__ xw, float* __restrict__ hist,
    u64* __restrict__ hbuf) {
    const int bid = blockIdx.x;
    const int dir = bid >> 5;
    const int wg  = bid & 31;
    const int tid = threadIdx.x;
    const int wv  = tid >> 6;       // wave id 0..7
    const int l   = tid & 63;
    const int j   = l & 7;          // gate row within wave's unit pair
    const int q   = l >> 3;         // k-slice
    const int g   = j >> 1;         // gate: 0=i 1=f 2=g 3=o
    const int p   = j & 1;          // unit parity
    const int u0  = wg * 16;
    const int unit = u0 + 2 * wv + p;
    const int grow = g * H + unit;  // global gate row

    const float* whh = dir ? whh_b : whh_f;
    float* histd = hist + (size_t)dir * L * H;
    u64* hb = hbuf + dir * 1024;    // [parity][512]

    // this lane's 64 Whh weights -> VGPRs
    float w[64];
    {
        const float* wp = whh + (size_t)grow * H + q * 64;
#pragma unroll
        for (int i = 0; i < 64; i += 4) {
            float4 v = *(const float4*)(wp + i);
            w[i] = v.x; w[i+1] = v.y; w[i+2] = v.z; w[i+3] = v.w;
        }
    }

    // h staging, parity-alternating; chunk stride 68 -> conflict-free f4 reads
    __shared__ float hstage[2][8 * 68];

    float c = 0.f;
    if (l < 2) c = c0[dir * H + u0 + 2 * wv + l];

    for (int s = 1; s <= L; ++s) {
        const int t = dir ? (L - s) : (s - 1);
        const int par = s & 1;

        // xw prefetch (lanes j<8 of every wave) — issued before the poll
        float xwv = 0.f;
        if (l < 8)
            xwv = xw[((size_t)(dir * L) + t) * G4H + wg * 64 + wv * 8 + j];

        // acquire h_{s-1}[tid] (own slot only)
        float hval;
        if (s == 1) {
            hval = h0[dir * H + tid];
        } else {
            u64* slot = hb + ((s - 1) & 1) * 512 + tid;
            u64 u;
            while (((u = __hip_atomic_load(slot, __ATOMIC_RELAXED,
                                           __HIP_MEMORY_SCOPE_AGENT)) >> 32)
                   != (u32)(s - 1))
                __builtin_amdgcn_s_sleep(1);
            hval = __uint_as_float((u32)u);
        }
        hstage[par][(tid >> 6) * 68 + (tid & 63)] = hval;   // 2-way: free
        __syncthreads();

        // dot: row j over slice q (16 f4 LDS reads, conflict-free broadcast)
        float acc = 0.f;
        const int base = q * 68;
#pragma unroll
        for (int i = 0; i < 64; i += 4) {
            float4 h4 = *(__shared__ float4*)&hstage[par][base + i];
            acc = fmaf(w[i], h4.x, fmaf(w[i+1], h4.y,
                  fmaf(w[i+2], h4.z, fmaf(w[i+3], h4.w, acc))));
        }
        // reduce across the 8 k-slices (q = lane>>3)
        acc += __shfl_xor(acc, 8);
        acc += __shfl_xor(acc, 16);
        acc += __shfl_xor(acc, 32);

        // gates (valid on lanes j<8; g==2 is the cell gate -> tanh)
        float pre = acc + xwv;
        float a2 = (g == 2) ? 2.f * pre : pre;
        float sg = 1.f / (1.f + __expf(-a2));
        float vg = (g == 2) ? (2.f * sg - 1.f) : sg;

        // unit update on lanes 0,1 (p = l)
        float gi = __shfl(vg, p);
        float gf = __shfl(vg, 2 + p);
        float gg = __shfl(vg, 4 + p);
        float go = __shfl(vg, 6 + p);
        float hout = 0.f;
        if (l < 2) {
            c = gf * c + gi * gg;
            float th = 2.f / (1.f + __expf(-2.f * c)) - 1.f;
            hout = go * th;
        }
        // publish this wave's 2 units (tagged, fire-and-forget)
        float h1 = __shfl(hout, 1);
        if (l == 0) {
            u64* bb = hb + par * 512 + u0 + 2 * wv;
            u64 e0 = ((u64)(u32)s << 32) | (u64)__float_as_uint(hout);
            u64 e1 = ((u64)(u32)s << 32) | (u64)__float_as_uint(h1);
            __hip_atomic_store(bb,     e0, __ATOMIC_RELAXED, __HIP_MEMORY_SCOPE_AGENT);
            __hip_atomic_store(bb + 1, e1, __ATOMIC_RELAXED, __HIP_MEMORY_SCOPE_AGENT);
        }
        if (l < 2)
            histd[(size_t)t * H + u0 + 2 * wv + l] = hout;
    }
}

// ---------------------------------------------------------------------------
// K3: feats[t][tag] = b_out[tag] + concat(hf,hb)[t] . w_out[tag]   (f32)
__global__ void k3_feats(const float* __restrict__ hist,
                         const float* __restrict__ wout,
                         const float* __restrict__ bout,
                         float* __restrict__ feats) {
    int t = blockIdx.x;
    int tid = threadIdx.x;
    int tag = tid >> 4;       // [0,20)
    int part = tid & 15;
    const float* h0p = hist + (size_t)t * H;
    const float* h1p = hist + (size_t)L * H + (size_t)t * H;
    int j0 = part * 64;
    float acc = 0.f;
    for (int jj = 0; jj < 64; jj += 4) {
        int j = j0 + jj;
        float4 w4 = *(const float4*)(wout + (size_t)tag * (2 * H) + j);
        float4 h4 = (j < H) ? *(const float4*)(h0p + j)
                            : *(const float4*)(h1p + (j - H));
        acc = fmaf(w4.x, h4.x, fmaf(w4.y, h4.y,
              fmaf(w4.z, h4.z, fmaf(w4.w, h4.w, acc))));
    }
    acc += __shfl_xor(acc, 8, 16);
    acc += __shfl_xor(acc, 4, 16);
    acc += __shfl_xor(acc, 2, 16);
    acc += __shfl_xor(acc, 1, 16);
    if (part == 0) feats[(size_t)t * NTAGS + tag] = acc + bout[tag];
}

// ---------------------------------------------------------------------------
// K4: Viterbi + backtrack, one wave. Batched shfls + index-carrying tree-max
// (exact first-max semantics: replace only on (v>) or (v== && idx<)).
__global__ void k4_viterbi(const float* __restrict__ feats,
                           const float* __restrict__ trans,
                           int* __restrict__ out) {
    __shared__ unsigned char bp[L * NTAGS];
    int lane = threadIdx.x;           // 64 threads
    bool act = lane < NTAGS;

    float trl[NTAGS];
#pragma unroll
    for (int p = 0; p < NTAGS; ++p)
        trl[p] = act ? trans[lane * NTAGS + p] : -1.0e30f;

    float fv = (lane == START_TAG) ? 0.f : -10000.f;
    float nf = act ? feats[lane] : 0.f;

    for (int t = 0; t < L; ++t) {
        float f = nf;
        if (act && t + 1 < L) nf = feats[(size_t)(t + 1) * NTAGS + lane];
        float tv[NTAGS];
        int   ti[NTAGS];
#pragma unroll
        for (int p = 0; p < NTAGS; ++p) {
            tv[p] = __shfl(fv, p) + trl[p];
            ti[p] = p;
        }
#pragma unroll
        for (int p = 0; p < 4; ++p) {
            bool take = (tv[p + 16] > tv[p]) ||
                        (tv[p + 16] == tv[p] && ti[p + 16] < ti[p]);
            if (take) { tv[p] = tv[p + 16]; ti[p] = ti[p + 16]; }
        }
#pragma unroll
        for (int w = 8; w >= 1; w >>= 1)
#pragma unroll
            for (int p = 0; p < 16; ++p) if (p < w) {
                bool take = (tv[p + w] > tv[p]) ||
                            (tv[p + w] == tv[p] && ti[p + w] < ti[p]);
                if (take) { tv[p] = tv[p + w]; ti[p] = ti[p + w]; }
            }
        fv = tv[0] + f;
        if (act) bp[t * NTAGS + lane] = (unsigned char)ti[0];
    }

    float ts = act ? fv + trans[STOP_TAG * NTAGS + lane] : -1.0e30f;
    int bi = lane;
#pragma unroll
    for (int off = 32; off; off >>= 1) {
        float ov = __shfl_down(ts, off);
        int   oi = __shfl_down(bi, off);
        if (ov > ts) { ts = ov; bi = oi; }
    }
    if (lane == 0) {
        int tag = bi;
        out[L - 1] = tag;
        for (int t = L - 1; t >= 1; --t) {
            tag = bp[t * NTAGS + tag];
            out[t - 1] = tag;
        }
    }
}

// ---------------------------------------------------------------------------
extern "C" void kernel_launch(void* const* d_in, const int* in_sizes, int n_in,
                              void* d_out, int out_size, void* d_ws, size_t ws_size,
                              hipStream_t stream) {
    const int*   sentence = (const int*)d_in[0];
    const float* embed    = (const float*)d_in[1];
    const float* wih_f    = (const float*)d_in[2];
    const float* whh_f    = (const float*)d_in[3];
    const float* bih_f    = (const float*)d_in[4];
    const float* bhh_f    = (const float*)d_in[5];
    const float* wih_b    = (const float*)d_in[6];
    const float* whh_b    = (const float*)d_in[7];
    const float* bih_b    = (const float*)d_in[8];
    const float* bhh_b    = (const float*)d_in[9];
    const float* h0       = (const float*)d_in[10];
    const float* c0       = (const float*)d_in[11];
    const float* wout     = (const float*)d_in[12];
    const float* bout     = (const float*)d_in[13];
    const float* trans    = (const float*)d_in[14];
    int* out = (int*)d_out;

    char* ws = (char*)d_ws;
    float* xw    = (float*)(ws + OFF_XW);
    float* hist  = (float*)(ws + OFF_HIST);
    float* feats = (float*)(ws + OFF_FEATS);
    u64*   hbuf  = (u64*)(ws + OFF_HBUF);

    k1_xw<<<dim3(32, 8, 2), 256, 0, stream>>>(sentence, embed, wih_f, wih_b,
                                              bih_f, bhh_f, bih_b, bhh_b, xw);
    k2_lstm<<<64, 512, 0, stream>>>(whh_f, whh_b, h0, c0, xw, hist, hbuf);
    k3_feats<<<L, 320, 0, stream>>>(hist, wout, bout, feats);
    k4_viterbi<<<1, 64, 0, stream>>>(feats, trans, out);
}

// Round 6
// 1604.522 us; speedup vs baseline: 1.3382x; 1.0627x over previous
//
#include <hip/hip_runtime.h>
#include <math.h>

typedef unsigned long long u64;
typedef unsigned int u32;

// Problem constants
#define L 512
#define E 300
#define H 512          // per-direction hidden
#define G4H 2048       // 4*H
#define NTAGS 20
#define START_TAG 18
#define STOP_TAG 19

#define KC 100         // k1 K-chunk (300 = 3*100)

// Workspace layout (bytes)
#define OFF_XW    0u          // f32 [2][512][2048] (permuted cols) = 8388608
#define OFF_HIST  8388608u    // f32 [2][512][512]  = 2097152
#define OFF_HBUF  10485760u   // u64 [2][2][512]    = 16384
#define OFF_FEATS 10502144u   // f32 [512][20]      = 40960

// ---------------------------------------------------------------------------
// K1: tiled GEMM  xw[dir][t][pos(n)] = embed[sent[t]] . wih[n] + bias(n).
// 64n x 64t tile, 4x4 microtile, K chunks of 100 staged in LDS.
// Column permutation pos(n), UNIT-MAJOR within each k2 WG's 64-block:
// u=n&511, g=n>>9 -> pos = (u>>4)*64 + (u&15)*4 + g.
__global__ __launch_bounds__(256) void k1_xw(
    const int* __restrict__ sentence, const float* __restrict__ embed,
    const float* __restrict__ wih_f, const float* __restrict__ wih_b,
    const float* __restrict__ bih_f, const float* __restrict__ bhh_f,
    const float* __restrict__ bih_b, const float* __restrict__ bhh_b,
    float* __restrict__ xw) {
    __shared__ float wST[KC][68];   // [k][n]
    __shared__ float xST[KC][68];   // [k][t]
    __shared__ int   sT[64];

    const int tid = threadIdx.x;
    const int tx = tid & 15;        // t micro index
    const int ty = tid >> 4;        // n micro index
    const int n_base = blockIdx.x * 64;
    const int t_base = blockIdx.y * 64;
    const int dir = blockIdx.z;
    const float* wih = dir ? wih_b : wih_f;
    const float* bih = dir ? bih_b : bih_f;
    const float* bhh = dir ? bhh_b : bhh_f;

    if (tid < 64) sT[tid] = sentence[t_base + tid];
    __syncthreads();

    float acc[4][4];
#pragma unroll
    for (int i = 0; i < 4; ++i)
#pragma unroll
        for (int j = 0; j < 4; ++j) acc[i][j] = 0.f;

    for (int kc = 0; kc < E; kc += KC) {
#pragma unroll
        for (int i = 0; i < 25; ++i) {
            int idx = i * 256 + tid;          // < 6400
            int row = idx / KC, col = idx % KC;
            wST[col][row] = wih[(size_t)(n_base + row) * E + kc + col];
        }
#pragma unroll
        for (int i = 0; i < 25; ++i) {
            int idx = i * 256 + tid;
            int trow = idx / KC, col = idx % KC;
            xST[col][trow] = embed[(size_t)sT[trow] * E + kc + col];
        }
        __syncthreads();

#pragma unroll 4
        for (int k = 0; k < KC; ++k) {
            float4 wv4 = *(const float4*)&wST[k][ty * 4];
            float4 xv4 = *(const float4*)&xST[k][tx * 4];
            float wv[4] = {wv4.x, wv4.y, wv4.z, wv4.w};
            float xv[4] = {xv4.x, xv4.y, xv4.z, xv4.w};
#pragma unroll
            for (int i = 0; i < 4; ++i)
#pragma unroll
                for (int j = 0; j < 4; ++j)
                    acc[i][j] = fmaf(wv[i], xv[j], acc[i][j]);
        }
        __syncthreads();
    }

#pragma unroll
    for (int i = 0; i < 4; ++i) {
        int n = n_base + ty * 4 + i;
        float b = bih[n] + bhh[n];
        int u = n & (H - 1), g = n >> 9;
        int pos = (u >> 4) * 64 + (u & 15) * 4 + g;   // unit-major
#pragma unroll
        for (int j = 0; j < 4; ++j) {
            int t = t_base + tx * 4 + j;
            xw[((size_t)(dir * L) + t) * G4H + pos] = acc[i][j] + b;
        }
    }
}

// ---------------------------------------------------------------------------
// K2: bidirectional LSTM recurrence. 64 WGs x 512 threads.
// FRONT (r3 style, arrival-overlapped): thread tid polls slot 'tid'; wave wv's
// 64 lanes hold h[64wv..64wv+64) -> readlane dot, lane l = local row l
// (unit jj=l>>2, gate g=l&3), 4 split accumulators.
// TAIL (distributed): wave wv reduces rows 8wv..8wv+8 (= units 2wv,2wv+1)
// from pbuf, computes gates, publishes its own 2 units immediately.
__global__ __launch_bounds__(512) void k2_lstm(
    const float* __restrict__ whh_f, const float* __restrict__ whh_b,
    const float* __restrict__ h0, const float* __restrict__ c0,
    const float* __restrict__ xw, float* __restrict__ hist,
    u64* __restrict__ hbuf) {
    const int bid = blockIdx.x;
    const int dir = bid >> 5;
    const int wg  = bid & 31;
    const int tid = threadIdx.x;
    const int wv  = tid >> 6;       // wave id 0..7 (= dot k-slice)
    const int l   = tid & 63;
    const int jj  = l >> 2;         // unit within WG (dot role)
    const int g   = l & 3;          // gate: 0=i 1=f 2=g 3=o
    const int grow = g * H + wg * 16 + jj;

    const float* whh = dir ? whh_b : whh_f;
    float* histd = hist + (size_t)dir * L * H;
    u64* hb = hbuf + dir * 1024;    // [parity][512]

    // this lane's 64 Whh weights (row grow, slice wv) -> VGPRs
    float w[64];
    {
        const float* wp = whh + (size_t)grow * H + wv * 64;
#pragma unroll
        for (int i = 0; i < 64; i += 4) {
            float4 v = *(const float4*)(wp + i);
            w[i] = v.x; w[i+1] = v.y; w[i+2] = v.z; w[i+3] = v.w;
        }
    }

    __shared__ float pbuf[2][8][68];   // [parity][slice][row(+pad)]

    // c state on lanes 0,4 of each wave: unit = wg*16 + 2*wv + (l>>2)
    float c = 0.f;
    if (l == 0 || l == 4) c = c0[dir * H + wg * 16 + 2 * wv + (l >> 2)];

    for (int s = 1; s <= L; ++s) {
        const int t = dir ? (L - s) : (s - 1);
        const int par = s & 1;

        // xw for this wave's tail rows (lanes 0..7; row = 8wv+l, unit-major)
        float xwv = 0.f;
        if (l < 8)
            xwv = xw[((size_t)(dir * L) + t) * G4H + wg * 64 + wv * 8 + l];

        // acquire h_{s-1}[tid] (own slot, hard spin)
        float hval;
        if (s == 1) {
            hval = h0[dir * H + tid];
        } else {
            u64* slot = hb + ((s - 1) & 1) * 512 + tid;
            u64 u;
            while (((u = __hip_atomic_load(slot, __ATOMIC_RELAXED,
                                           __HIP_MEMORY_SCOPE_AGENT)) >> 32)
                   != (u32)(s - 1)) { }
            hval = __uint_as_float((u32)u);
        }

        // dot: row l over slice wv, via readlane broadcast; 4 accumulators
        float a0 = 0.f, a1 = 0.f, a2 = 0.f, a3 = 0.f;
#pragma unroll
        for (int i = 0; i < 64; i += 4) {
            float h0v = __uint_as_float((u32)__builtin_amdgcn_readlane(
                            (int)__float_as_uint(hval), i));
            float h1v = __uint_as_float((u32)__builtin_amdgcn_readlane(
                            (int)__float_as_uint(hval), i + 1));
            float h2v = __uint_as_float((u32)__builtin_amdgcn_readlane(
                            (int)__float_as_uint(hval), i + 2));
            float h3v = __uint_as_float((u32)__builtin_amdgcn_readlane(
                            (int)__float_as_uint(hval), i + 3));
            a0 = fmaf(w[i],     h0v, a0);
            a1 = fmaf(w[i + 1], h1v, a1);
            a2 = fmaf(w[i + 2], h2v, a2);
            a3 = fmaf(w[i + 3], h3v, a3);
        }
        pbuf[par][wv][l] = (a0 + a1) + (a2 + a3);
        __syncthreads();

        // distributed tail: wave wv handles rows 8wv..8wv+8 (units 2wv,2wv+1)
        float part = pbuf[par][l >> 3][8 * wv + (l & 7)];
        part += __shfl_xor(part, 8);
        part += __shfl_xor(part, 16);
        part += __shfl_xor(part, 32);
        // every lane now holds row (8wv + (l&7))'s sum; gates valid on l<8
        float pre = part + xwv;
        float aa = (g == 2) ? 2.f * pre : pre;       // tanh = 2*sig(2x)-1
        float sg = 1.f / (1.f + __expf(-aa));
        float vg = (g == 2) ? (2.f * sg - 1.f) : sg;
        float gi = __shfl(vg, (l & 4));
        float gf = __shfl(vg, (l & 4) + 1);
        float gg = __shfl(vg, (l & 4) + 2);
        float go = __shfl(vg, (l & 4) + 3);
        if (l == 0 || l == 4) {
            c = gf * c + gi * gg;
            float th = 2.f / (1.f + __expf(-2.f * c)) - 1.f;
            float hout = go * th;
            int u = wg * 16 + 2 * wv + (l >> 2);
            u64 e = ((u64)(u32)s << 32) | (u64)__float_as_uint(hout);
            __hip_atomic_store(hb + par * 512 + u, e,
                               __ATOMIC_RELAXED, __HIP_MEMORY_SCOPE_AGENT);
            histd[(size_t)t * H + u] = hout;
        }
        // pbuf parity double-buffer + collective barrier covers reuse hazards
    }
}

// ---------------------------------------------------------------------------
// K3: feats[t][tag] = b_out[tag] + concat(hf,hb)[t] . w_out[tag]   (f32)
__global__ void k3_feats(const float* __restrict__ hist,
                         const float* __restrict__ wout,
                         const float* __restrict__ bout,
                         float* __restrict__ feats) {
    int t = blockIdx.x;
    int tid = threadIdx.x;
    int tag = tid >> 4;       // [0,20)
    int part = tid & 15;
    const float* h0p = hist + (size_t)t * H;
    const float* h1p = hist + (size_t)L * H + (size_t)t * H;
    int j0 = part * 64;
    float acc = 0.f;
    for (int jj = 0; jj < 64; jj += 4) {
        int j = j0 + jj;
        float4 w4 = *(const float4*)(wout + (size_t)tag * (2 * H) + j);
        float4 h4 = (j < H) ? *(const float4*)(h0p + j)
                            : *(const float4*)(h1p + (j - H));
        acc = fmaf(w4.x, h4.x, fmaf(w4.y, h4.y,
              fmaf(w4.z, h4.z, fmaf(w4.w, h4.w, acc))));
    }
    acc += __shfl_xor(acc, 8, 16);
    acc += __shfl_xor(acc, 4, 16);
    acc += __shfl_xor(acc, 2, 16);
    acc += __shfl_xor(acc, 1, 16);
    if (part == 0) feats[(size_t)t * NTAGS + tag] = acc + bout[tag];
}

// ---------------------------------------------------------------------------
// K4: Viterbi + backtrack, one wave. Batched shfls + index-carrying tree-max
// (exact first-max semantics).
__global__ void k4_viterbi(const float* __restrict__ feats,
                           const float* __restrict__ trans,
                           int* __restrict__ out) {
    __shared__ unsigned char bp[L * NTAGS];
    int lane = threadIdx.x;           // 64 threads
    bool act = lane < NTAGS;

    float trl[NTAGS];
#pragma unroll
    for (int p = 0; p < NTAGS; ++p)
        trl[p] = act ? trans[lane * NTAGS + p] : -1.0e30f;

    float fv = (lane == START_TAG) ? 0.f : -10000.f;
    float nf = act ? feats[lane] : 0.f;

    for (int t = 0; t < L; ++t) {
        float f = nf;
        if (act && t + 1 < L) nf = feats[(size_t)(t + 1) * NTAGS + lane];
        float tv[NTAGS];
        int   ti[NTAGS];
#pragma unroll
        for (int p = 0; p < NTAGS; ++p) {
            tv[p] = __shfl(fv, p) + trl[p];
            ti[p] = p;
        }
#pragma unroll
        for (int p = 0; p < 4; ++p) {
            bool take = (tv[p + 16] > tv[p]) ||
                        (tv[p + 16] == tv[p] && ti[p + 16] < ti[p]);
            if (take) { tv[p] = tv[p + 16]; ti[p] = ti[p + 16]; }
        }
#pragma unroll
        for (int w = 8; w >= 1; w >>= 1)
#pragma unroll
            for (int p = 0; p < 16; ++p) if (p < w) {
                bool take = (tv[p + w] > tv[p]) ||
                            (tv[p + w] == tv[p] && ti[p + w] < ti[p]);
                if (take) { tv[p] = tv[p + w]; ti[p] = ti[p + w]; }
            }
        fv = tv[0] + f;
        if (act) bp[t * NTAGS + lane] = (unsigned char)ti[0];
    }

    float ts = act ? fv + trans[STOP_TAG * NTAGS + lane] : -1.0e30f;
    int bi = lane;
#pragma unroll
    for (int off = 32; off; off >>= 1) {
        float ov = __shfl_down(ts, off);
        int   oi = __shfl_down(bi, off);
        if (ov > ts) { ts = ov; bi = oi; }
    }
    if (lane == 0) {
        int tag = bi;
        out[L - 1] = tag;
        for (int t = L - 1; t >= 1; --t) {
            tag = bp[t * NTAGS + tag];
            out[t - 1] = tag;
        }
    }
}

// ---------------------------------------------------------------------------
extern "C" void kernel_launch(void* const* d_in, const int* in_sizes, int n_in,
                              void* d_out, int out_size, void* d_ws, size_t ws_size,
                              hipStream_t stream) {
    const int*   sentence = (const int*)d_in[0];
    const float* embed    = (const float*)d_in[1];
    const float* wih_f    = (const float*)d_in[2];
    const float* whh_f    = (const float*)d_in[3];
    const float* bih_f    = (const float*)d_in[4];
    const float* bhh_f    = (const float*)d_in[5];
    const float* wih_b    = (const float*)d_in[6];
    const float* whh_b    = (const float*)d_in[7];
    const float* bih_b    = (const float*)d_in[8];
    const float* bhh_b    = (const float*)d_in[9];
    const float* h0       = (const float*)d_in[10];
    const float* c0       = (const float*)d_in[11];
    const float* wout     = (const float*)d_in[12];
    const float* bout     = (const float*)d_in[13];
    const float* trans    = (const float*)d_in[14];
    int* out = (int*)d_out;

    char* ws = (char*)d_ws;
    float* xw    = (float*)(ws + OFF_XW);
    float* hist  = (float*)(ws + OFF_HIST);
    float* feats = (float*)(ws + OFF_FEATS);
    u64*   hbuf  = (u64*)(ws + OFF_HBUF);

    k1_xw<<<dim3(32, 8, 2), 256, 0, stream>>>(sentence, embed, wih_f, wih_b,
                                              bih_f, bhh_f, bih_b, bhh_b, xw);
    k2_lstm<<<64, 512, 0, stream>>>(whh_f, whh_b, h0, c0, xw, hist, hbuf);
    k3_feats<<<L, 320, 0, stream>>>(hist, wout, bout, feats);
    k4_viterbi<<<1, 64, 0, stream>>>(feats, trans, out);
}

// Round 7
// 1365.052 us; speedup vs baseline: 1.5730x; 1.1754x over previous
//
#include <hip/hip_runtime.h>
#include <math.h>

typedef unsigned long long u64;
typedef unsigned int u32;

// Problem constants
#define L 512
#define E 300
#define H 512          // per-direction hidden
#define G4H 2048       // 4*H
#define NTAGS 20
#define START_TAG 18
#define STOP_TAG 19

#define KC 100         // k1 K-chunk (300 = 3*100)

// Workspace layout (bytes)
#define OFF_XW    0u          // f32 [2][512][2048] (permuted cols) = 8388608
#define OFF_HIST  8388608u    // f32 [2][512][512]  = 2097152
#define OFF_HBUF  10485760u   // u64 [2][2][512]    = 16384
#define OFF_FEATS 10502144u   // f32 [512][20]      = 40960

// ---------------------------------------------------------------------------
// K1: tiled GEMM  xw[dir][t][pos(n)] = embed[sent[t]] . wih[n] + bias(n).
// 64n x 64t tile, 4x4 microtile, K chunks of 100 staged in LDS.
// pos(n) gate-major within each k2 WG's 64-block: u=n&511, g=n>>9 ->
// pos = (u>>4)*64 + g*16 + (u&15)  -> k2 wave0 tail reads xw[t][wg*64+l].
__global__ __launch_bounds__(256) void k1_xw(
    const int* __restrict__ sentence, const float* __restrict__ embed,
    const float* __restrict__ wih_f, const float* __restrict__ wih_b,
    const float* __restrict__ bih_f, const float* __restrict__ bhh_f,
    const float* __restrict__ bih_b, const float* __restrict__ bhh_b,
    float* __restrict__ xw) {
    __shared__ float wST[KC][68];   // [k][n]
    __shared__ float xST[KC][68];   // [k][t]
    __shared__ int   sT[64];

    const int tid = threadIdx.x;
    const int tx = tid & 15;        // t micro index
    const int ty = tid >> 4;        // n micro index
    const int n_base = blockIdx.x * 64;
    const int t_base = blockIdx.y * 64;
    const int dir = blockIdx.z;
    const float* wih = dir ? wih_b : wih_f;
    const float* bih = dir ? bih_b : bih_f;
    const float* bhh = dir ? bhh_b : bhh_f;

    if (tid < 64) sT[tid] = sentence[t_base + tid];
    __syncthreads();

    float acc[4][4];
#pragma unroll
    for (int i = 0; i < 4; ++i)
#pragma unroll
        for (int j = 0; j < 4; ++j) acc[i][j] = 0.f;

    for (int kc = 0; kc < E; kc += KC) {
#pragma unroll
        for (int i = 0; i < 25; ++i) {
            int idx = i * 256 + tid;          // < 6400
            int row = idx / KC, col = idx % KC;
            wST[col][row] = wih[(size_t)(n_base + row) * E + kc + col];
        }
#pragma unroll
        for (int i = 0; i < 25; ++i) {
            int idx = i * 256 + tid;
            int trow = idx / KC, col = idx % KC;
            xST[col][trow] = embed[(size_t)sT[trow] * E + kc + col];
        }
        __syncthreads();

#pragma unroll 4
        for (int k = 0; k < KC; ++k) {
            float4 wv4 = *(const float4*)&wST[k][ty * 4];
            float4 xv4 = *(const float4*)&xST[k][tx * 4];
            float wv[4] = {wv4.x, wv4.y, wv4.z, wv4.w};
            float xv[4] = {xv4.x, xv4.y, xv4.z, xv4.w};
#pragma unroll
            for (int i = 0; i < 4; ++i)
#pragma unroll
                for (int j = 0; j < 4; ++j)
                    acc[i][j] = fmaf(wv[i], xv[j], acc[i][j]);
        }
        __syncthreads();
    }

#pragma unroll
    for (int i = 0; i < 4; ++i) {
        int n = n_base + ty * 4 + i;
        float b = bih[n] + bhh[n];
        int u = n & (H - 1), g = n >> 9;
        int pos = (u >> 4) * 64 + g * 16 + (u & 15);   // gate-major in block
#pragma unroll
        for (int j = 0; j < 4; ++j) {
            int t = t_base + tx * 4 + j;
            xw[((size_t)(dir * L) + t) * G4H + pos] = acc[i][j] + b;
        }
    }
}

// ---------------------------------------------------------------------------
// K2: bidirectional LSTM recurrence. 64 WGs x 512 threads (r3 skeleton).
// Thread tid polls slot 'tid' (3-deep pipelined -> sampling ~RT/3).
// Wave wv holds h[64wv..64wv+64) in-lane -> readlane dot (4 split accs),
// lane l = gate-major row (g=l>>4, j=l&15). Cross-wave reduce via pbuf +
// ONE barrier; wave0 funnel tail: gates + single coalesced 128B publish.
__global__ __launch_bounds__(512) void k2_lstm(
    const float* __restrict__ whh_f, const float* __restrict__ whh_b,
    const float* __restrict__ h0, const float* __restrict__ c0,
    const float* __restrict__ xw, float* __restrict__ hist,
    u64* __restrict__ hbuf) {
    const int bid = blockIdx.x;
    const int dir = bid >> 5;
    const int wg  = bid & 31;
    const int tid = threadIdx.x;
    const int wv  = tid >> 6;       // wave id = dot k-slice
    const int l   = tid & 63;
    const int g   = l >> 4;         // gate: 0=i 1=f 2=g 3=o
    const int j   = l & 15;         // unit within WG
    const int grow = g * H + wg * 16 + j;

    const float* whh = dir ? whh_b : whh_f;
    float* histd = hist + (size_t)dir * L * H;
    u64* hb = hbuf + dir * 1024;    // [parity][512]

    // this lane's 64 Whh weights (row grow, slice wv) -> VGPRs
    float w[64];
    {
        const float* wp = whh + (size_t)grow * H + wv * 64;
#pragma unroll
        for (int i = 0; i < 64; i += 4) {
            float4 v = *(const float4*)(wp + i);
            w[i] = v.x; w[i+1] = v.y; w[i+2] = v.z; w[i+3] = v.w;
        }
    }

    __shared__ float pbuf[2][8][68];   // [parity][slice][row(+pad)]

    // c state lives on wave0 lanes 0..15 (unit = wg*16 + tid)
    float c = (tid < 16) ? c0[dir * H + wg * 16 + tid] : 0.f;

    for (int s = 1; s <= L; ++s) {
        const int t = dir ? (L - s) : (s - 1);
        const int par = s & 1;

        // xw for wave0's tail rows: coalesced 64-lane load (gate-major layout)
        float xwv = 0.f;
        if (tid < 64)
            xwv = xw[((size_t)(dir * L) + t) * G4H + wg * 64 + l];

        // ---- acquire h_{s-1}[tid]: 3-deep pipelined poll on own slot ----
        float hval;
        if (s == 1) {
            hval = h0[dir * H + tid];
        } else {
            const u32 want = (u32)(s - 1);
            u64* slot = hb + ((s - 1) & 1) * 512 + tid;
            u64 v0 = __hip_atomic_load(slot, __ATOMIC_RELAXED, __HIP_MEMORY_SCOPE_AGENT);
            u64 v1 = __hip_atomic_load(slot, __ATOMIC_RELAXED, __HIP_MEMORY_SCOPE_AGENT);
            u64 v2 = __hip_atomic_load(slot, __ATOMIC_RELAXED, __HIP_MEMORY_SCOPE_AGENT);
            while ((u32)(v0 >> 32) != want) {
                v0 = v1; v1 = v2;
                v2 = __hip_atomic_load(slot, __ATOMIC_RELAXED, __HIP_MEMORY_SCOPE_AGENT);
            }
            hval = __uint_as_float((u32)v0);
        }

        // ---- dot: row l over slice wv via readlane broadcast, 4 accs ----
        float a0 = 0.f, a1 = 0.f, a2 = 0.f, a3 = 0.f;
#pragma unroll
        for (int i = 0; i < 64; i += 4) {
            float h0v = __uint_as_float((u32)__builtin_amdgcn_readlane(
                            (int)__float_as_uint(hval), i));
            float h1v = __uint_as_float((u32)__builtin_amdgcn_readlane(
                            (int)__float_as_uint(hval), i + 1));
            float h2v = __uint_as_float((u32)__builtin_amdgcn_readlane(
                            (int)__float_as_uint(hval), i + 2));
            float h3v = __uint_as_float((u32)__builtin_amdgcn_readlane(
                            (int)__float_as_uint(hval), i + 3));
            a0 = fmaf(w[i],     h0v, a0);
            a1 = fmaf(w[i + 1], h1v, a1);
            a2 = fmaf(w[i + 2], h2v, a2);
            a3 = fmaf(w[i + 3], h3v, a3);
        }
        pbuf[par][wv][l] = (a0 + a1) + (a2 + a3);
        __syncthreads();

        // ---- wave0 funnel tail: reduce 8 partials, gates, publish ----
        if (tid < 64) {
            float tot = 0.f;
#pragma unroll
            for (int p = 0; p < 8; ++p) tot += pbuf[par][p][l];
            float pre = tot + xwv;
            float aa = (g == 2) ? 2.f * pre : pre;       // tanh = 2*sig(2x)-1
            float sg = 1.f / (1.f + __expf(-aa));
            float vg = (g == 2) ? (2.f * sg - 1.f) : sg;
            float gi = __shfl(vg, j);
            float gf = __shfl(vg, 16 + j);
            float gg = __shfl(vg, 32 + j);
            float go = __shfl(vg, 48 + j);
            if (tid < 16) {
                c = gf * c + gi * gg;
                float th = 2.f / (1.f + __expf(-2.f * c)) - 1.f;
                float hout = go * th;
                // single coalesced 128B publish (16 lanes x 8B, contiguous)
                u64 e = ((u64)(u32)s << 32) | (u64)__float_as_uint(hout);
                __hip_atomic_store(hb + par * 512 + wg * 16 + tid, e,
                                   __ATOMIC_RELAXED, __HIP_MEMORY_SCOPE_AGENT);
                histd[(size_t)t * H + wg * 16 + tid] = hout;
            }
        }
        // pbuf parity double-buffer + the single barrier covers reuse
    }
}

// ---------------------------------------------------------------------------
// K3: feats[t][tag] = b_out[tag] + concat(hf,hb)[t] . w_out[tag]   (f32)
__global__ void k3_feats(const float* __restrict__ hist,
                         const float* __restrict__ wout,
                         const float* __restrict__ bout,
                         float* __restrict__ feats) {
    int t = blockIdx.x;
    int tid = threadIdx.x;
    int tag = tid >> 4;       // [0,20)
    int part = tid & 15;
    const float* h0p = hist + (size_t)t * H;
    const float* h1p = hist + (size_t)L * H + (size_t)t * H;
    int j0 = part * 64;
    float acc = 0.f;
    for (int jj = 0; jj < 64; jj += 4) {
        int j = j0 + jj;
        float4 w4 = *(const float4*)(wout + (size_t)tag * (2 * H) + j);
        float4 h4 = (j < H) ? *(const float4*)(h0p + j)
                            : *(const float4*)(h1p + (j - H));
        acc = fmaf(w4.x, h4.x, fmaf(w4.y, h4.y,
              fmaf(w4.z, h4.z, fmaf(w4.w, h4.w, acc))));
    }
    acc += __shfl_xor(acc, 8, 16);
    acc += __shfl_xor(acc, 4, 16);
    acc += __shfl_xor(acc, 2, 16);
    acc += __shfl_xor(acc, 1, 16);
    if (part == 0) feats[(size_t)t * NTAGS + tag] = acc + bout[tag];
}

// ---------------------------------------------------------------------------
// K4: Viterbi + backtrack, one wave. Batched shfls + index-carrying tree-max
// (exact first-max semantics).
__global__ void k4_viterbi(const float* __restrict__ feats,
                           const float* __restrict__ trans,
                           int* __restrict__ out) {
    __shared__ unsigned char bp[L * NTAGS];
    int lane = threadIdx.x;           // 64 threads
    bool act = lane < NTAGS;

    float trl[NTAGS];
#pragma unroll
    for (int p = 0; p < NTAGS; ++p)
        trl[p] = act ? trans[lane * NTAGS + p] : -1.0e30f;

    float fv = (lane == START_TAG) ? 0.f : -10000.f;
    float nf = act ? feats[lane] : 0.f;

    for (int t = 0; t < L; ++t) {
        float f = nf;
        if (act && t + 1 < L) nf = feats[(size_t)(t + 1) * NTAGS + lane];
        float tv[NTAGS];
        int   ti[NTAGS];
#pragma unroll
        for (int p = 0; p < NTAGS; ++p) {
            tv[p] = __shfl(fv, p) + trl[p];
            ti[p] = p;
        }
#pragma unroll
        for (int p = 0; p < 4; ++p) {
            bool take = (tv[p + 16] > tv[p]) ||
                        (tv[p + 16] == tv[p] && ti[p + 16] < ti[p]);
            if (take) { tv[p] = tv[p + 16]; ti[p] = ti[p + 16]; }
        }
#pragma unroll
        for (int w = 8; w >= 1; w >>= 1)
#pragma unroll
            for (int p = 0; p < 16; ++p) if (p < w) {
                bool take = (tv[p + w] > tv[p]) ||
                            (tv[p + w] == tv[p] && ti[p + w] < ti[p]);
                if (take) { tv[p] = tv[p + w]; ti[p] = ti[p + w]; }
            }
        fv = tv[0] + f;
        if (act) bp[t * NTAGS + lane] = (unsigned char)ti[0];
    }

    float ts = act ? fv + trans[STOP_TAG * NTAGS + lane] : -1.0e30f;
    int bi = lane;
#pragma unroll
    for (int off = 32; off; off >>= 1) {
        float ov = __shfl_down(ts, off);
        int   oi = __shfl_down(bi, off);
        if (ov > ts) { ts = ov; bi = oi; }
    }
    if (lane == 0) {
        int tag = bi;
        out[L - 1] = tag;
        for (int t = L - 1; t >= 1; --t) {
            tag = bp[t * NTAGS + tag];
            out[t - 1] = tag;
        }
    }
}

// ---------------------------------------------------------------------------
extern "C" void kernel_launch(void* const* d_in, const int* in_sizes, int n_in,
                              void* d_out, int out_size, void* d_ws, size_t ws_size,
                              hipStream_t stream) {
    const int*   sentence = (const int*)d_in[0];
    const float* embed    = (const float*)d_in[1];
    const float* wih_f    = (const float*)d_in[2];
    const float* whh_f    = (const float*)d_in[3];
    const float* bih_f    = (const float*)d_in[4];
    const float* bhh_f    = (const float*)d_in[5];
    const float* wih_b    = (const float*)d_in[6];
    const float* whh_b    = (const float*)d_in[7];
    const float* bih_b    = (const float*)d_in[8];
    const float* bhh_b    = (const float*)d_in[9];
    const float* h0       = (const float*)d_in[10];
    const float* c0       = (const float*)d_in[11];
    const float* wout     = (const float*)d_in[12];
    const float* bout     = (const float*)d_in[13];
    const float* trans    = (const float*)d_in[14];
    int* out = (int*)d_out;

    char* ws = (char*)d_ws;
    float* xw    = (float*)(ws + OFF_XW);
    float* hist  = (float*)(ws + OFF_HIST);
    float* feats = (float*)(ws + OFF_FEATS);
    u64*   hbuf  = (u64*)(ws + OFF_HBUF);

    k1_xw<<<dim3(32, 8, 2), 256, 0, stream>>>(sentence, embed, wih_f, wih_b,
                                              bih_f, bhh_f, bih_b, bhh_b, xw);
    k2_lstm<<<64, 512, 0, stream>>>(whh_f, whh_b, h0, c0, xw, hist, hbuf);
    k3_feats<<<L, 320, 0, stream>>>(hist, wout, bout, feats);
    k4_viterbi<<<1, 64, 0, stream>>>(feats, trans, out);
}